// Round 6
// baseline (401.691 us; speedup 1.0000x reference)
//
#include <hip/hip_runtime.h>
#include <hip/hip_bf16.h>

#define BB   16384
#define F    40
#define WPB  8     // waves per workgroup (8 -> 69 KB LDS -> 2 WGs/CU = 16 waves/CU)
#define NBW  4     // batches per wave, software-pipelined via LDS staging
#define XROW 72    // LDS X row stride in bf16 (144 B: 16-B aligned, bank-uniform reads)

typedef __bf16 bf16;
typedef __bf16 bf16x8 __attribute__((ext_vector_type(8)));
typedef __bf16 bf16x4 __attribute__((ext_vector_type(4)));
typedef short  s16x4  __attribute__((ext_vector_type(4)));
typedef float  f32x4  __attribute__((ext_vector_type(4)));

// MFMA 16x16x32 bf16 layouts:
//   A-frag: lane holds A[m = lane&15][k = (lane>>4)*8 + j]   (8 consec k)
//   B-frag: lane holds B[k = (lane>>4)*8 + j][n = lane&15]
//   C/D   : lane holds C[row = (lane>>4)*4 + r][col = lane&15]
// MFMA 16x16x16 bf16: A-frag lane holds A[m=lane&15][k=(lane>>4)*4+j] (4 consec k).
// KEY: a 16x16 C-output bf16x4 IS bit-for-bit the B-frag of that tile (and the
// A-frag of its transpose) for mfma16 -> product chaining with no data movement.
//
// R6 structural change: steady-state compute touches ONLY lgkmcnt.
//  - weights live in LDS (staged once, one barrier, then waves fully decoupled)
//  - X staged per-wave into private LDS bf16 buffer; next batch's X loaded in two
//    5-load chunks whose vmcnt waits land ~600+cyc later with an empty queue
//    (R1 lesson: any other vmem between prefetch and consume poisons vmcnt).

__device__ __forceinline__ bf16x4 cvt4(float4 a) {
    bf16x4 f;
    f[0] = (bf16)a.x; f[1] = (bf16)a.y; f[2] = (bf16)a.z; f[3] = (bf16)a.w;
    return f;
}
__device__ __forceinline__ bf16x8 cvt8(float4 a, float4 b) {
    bf16x8 f;
    f[0] = (bf16)a.x; f[1] = (bf16)a.y; f[2] = (bf16)a.z; f[3] = (bf16)a.w;
    f[4] = (bf16)b.x; f[5] = (bf16)b.y; f[6] = (bf16)b.z; f[7] = (bf16)b.w;
    return f;
}
__device__ __forceinline__ bf16x4 pack4(f32x4 a) {
    bf16x4 f;
    f[0] = (bf16)a[0]; f[1] = (bf16)a[1]; f[2] = (bf16)a[2]; f[3] = (bf16)a[3];
    return f;
}
__device__ __forceinline__ f32x4 mfma32(bf16x8 a, bf16x8 b, f32x4 c) {
    return __builtin_amdgcn_mfma_f32_16x16x32_bf16(a, b, c, 0, 0, 0);
}
__device__ __forceinline__ f32x4 mfma16(bf16x4 a, bf16x4 b, f32x4 c) {
#if __has_builtin(__builtin_amdgcn_mfma_f32_16x16x16_bf16)
    return __builtin_amdgcn_mfma_f32_16x16x16_bf16(a, b, c, 0, 0, 0);
#else
    return __builtin_amdgcn_mfma_f32_16x16x16bf16_1k(
        __builtin_bit_cast(s16x4, a), __builtin_bit_cast(s16x4, b), c, 0, 0, 0);
#endif
}

// ---- prep: block0 computes G = Wq*Wk^T via MFMA and packs it; blocks 1,2 pack Wv/Wr ----
__global__ __launch_bounds__(256)
void prep_weights(const float* __restrict__ Wq, const float* __restrict__ Wk,
                  const float* __restrict__ Wv, const float* __restrict__ Wr,
                  bf16* __restrict__ ws)
{
    const int tid = threadIdx.x;
    if (blockIdx.x > 0) {
        const float* W = (blockIdx.x == 1) ? Wv : Wr;
        bf16* dst = ws + 4096 * blockIdx.x;
        for (int f = tid; f < 4096; f += 256) {
            int j = f & 7, ln = (f >> 3) & 63, kt = (f >> 9) & 1, nt = f >> 10;
            dst[f] = (bf16)W[(kt * 32 + (ln >> 4) * 8 + j) * 64 + nt * 16 + (ln & 15)];
        }
        return;
    }
    __shared__ float Gs[64 * 64];
    if (tid < 64) {   // one wave: G[d][d'] = sum_e Wq[d][e] * Wk[d'][e]
        const int l16 = tid & 15, quad = tid >> 4;
        bf16x8 aq[4][2], ak[4][2];
        #pragma unroll
        for (int mt = 0; mt < 4; ++mt)
            #pragma unroll
            for (int kt = 0; kt < 2; ++kt) {
                const float* pq = Wq + (mt * 16 + l16) * 64 + kt * 32 + quad * 8;
                const float* pk = Wk + (mt * 16 + l16) * 64 + kt * 32 + quad * 8;
                aq[mt][kt] = cvt8(*(const float4*)pq, *(const float4*)(pq + 4));
                ak[mt][kt] = cvt8(*(const float4*)pk, *(const float4*)(pk + 4));
            }
        #pragma unroll
        for (int mt = 0; mt < 4; ++mt)
            #pragma unroll
            for (int nt = 0; nt < 4; ++nt) {
                f32x4 acc = {0.f, 0.f, 0.f, 0.f};
                acc = mfma32(aq[mt][0], ak[nt][0], acc);
                acc = mfma32(aq[mt][1], ak[nt][1], acc);
                #pragma unroll
                for (int r = 0; r < 4; ++r)
                    Gs[(mt * 16 + quad * 4 + r) * 64 + nt * 16 + l16] = acc[r];
            }
    }
    __syncthreads();
    for (int f = tid; f < 4096; f += 256) {
        int j = f & 7, ln = (f >> 3) & 63, kt = (f >> 9) & 1, nt = f >> 10;
        ws[f] = (bf16)Gs[(kt * 32 + (ln >> 4) * 8 + j) * 64 + nt * 16 + (ln & 15)];
    }
}

// ---- main: 8 waves/WG, 4 batches/wave, weights+X in LDS, lgkm-only compute ----
__global__ __launch_bounds__(64 * WPB)
void attn_fused(const float* __restrict__ X, const bf16* __restrict__ wfrag,
                float* __restrict__ Out)
{
    __shared__ bf16 WS[3 * 4096];          // fragment-packed G / Wv / Wr (24 KB)
    __shared__ bf16 XS[WPB][F * XROW];     // per-wave private X buffer (5.6 KB each)

    const int tid  = threadIdx.x;
    const int lane = tid & 63;
    const int wav  = tid >> 6;
    const int l16  = lane & 15;
    const int quad = lane >> 4;

    {   // stage weights -> LDS: 24576 B = 1536 float4; the kernel's ONLY barrier
        const float4* src = (const float4*)wfrag;
        float4* dst = (float4*)WS;
        #pragma unroll
        for (int j = 0; j < 3; ++j)
            dst[tid + 512 * j] = src[tid + 512 * j];
    }
    __syncthreads();

    bf16* XSw  = &XS[wav][0];
    // stage dst per lane: element (lane + 64t) of batch -> row quad+4t, col 4*l16
    bf16* sdst = XSw + quad * XROW + l16 * 4;              // + t*4*XROW

    // weight frag base: frag f is 64 lanes x 8 bf16; addr = base + lane*16B + f*1024B
    const bf16* gL = WS           + lane * 8;   // B-frags of G  == A-frags of G^T
    const bf16* vL = WS + 4096    + lane * 8;   // B-frags of Wv
    const bf16* rL = WS + 2*4096  + lane * 8;   // B-frags of Wr == A-frags of Wr^T

    int rowm[3];
    #pragma unroll
    for (int mt = 0; mt < 3; ++mt) {
        int r = mt * 16 + l16; rowm[mt] = (r >= F) ? (F - 1) : r;  // clamp pad rows
    }

    const size_t b0 = ((size_t)blockIdx.x * WPB + wav) * NBW;

    {   // prologue: stage batch b0 (10x coalesced dwordx4 -> cvt -> ds_write_b64)
        const float* Xs = X + b0 * (F * 64) + lane * 4;
        float4 xr[10];
        #pragma unroll
        for (int t = 0; t < 10; ++t) xr[t] = *(const float4*)(Xs + t * 256);
        #pragma unroll
        for (int t = 0; t < 10; ++t) *(bf16x4*)(sdst + t * 4 * XROW) = cvt4(xr[t]);
    }

    #pragma unroll 1
    for (int i = 0; i < NBW; ++i) {
        const size_t b = b0 + i;
        const bool more = (i + 1 < NBW);
        const float* Xn = X + (b + 1) * (F * 64) + lane * 4;  // next batch source

        // ---- batch top: X frags from LDS (bf16 already; zero conversion) ----
        bf16x8 xf[3][2];
        bf16x4 xa[3][4];
        #pragma unroll
        for (int mt = 0; mt < 3; ++mt) {
            const bf16* rb = XSw + rowm[mt] * XROW;
            #pragma unroll
            for (int kt = 0; kt < 2; ++kt)
                xf[mt][kt] = *(const bf16x8*)(rb + kt * 32 + quad * 8);
            #pragma unroll
            for (int kt = 0; kt < 4; ++kt)
                xa[mt][kt] = *(const bf16x4*)(rb + kt * 16 + quad * 4);
        }

        // ---- q'^T = G^T @ X^T : lane = q'[m=16nt+l16][e=16mt+4*quad+r] ----
        bf16x4 pkQ[4][3];
        #pragma unroll
        for (int mt = 0; mt < 4; ++mt) {
            bf16x8 a0 = *(const bf16x8*)(gL + (mt * 2 + 0) * 512);
            bf16x8 a1 = *(const bf16x8*)(gL + (mt * 2 + 1) * 512);
            #pragma unroll
            for (int nt = 0; nt < 3; ++nt) {
                f32x4 acc = {0.f, 0.f, 0.f, 0.f};
                acc = mfma32(a0, xf[nt][0], acc);
                acc = mfma32(a1, xf[nt][1], acc);
                pkQ[mt][nt] = pack4(acc);
            }
        }

        // ---- S^T = X @ q'^T via mfma16 (pkQ IS the B-frag; pure register chain) ----
        f32x4 sacc[3][3];
        #pragma unroll
        for (int mt = 0; mt < 3; ++mt)
            #pragma unroll
            for (int nt = 0; nt < 3; ++nt) {
                f32x4 acc = {0.f, 0.f, 0.f, 0.f};
                #pragma unroll
                for (int kt = 0; kt < 4; ++kt)
                    acc = mfma16(xa[mt][kt], pkQ[kt][nt], acc);
                sacc[mt][nt] = acc;
            }

        // ---- softmax over k': in-lane 12 values + 2 shfls -> pkP regs ----
        // lane holds S^T[k'=16mt+4*quad+r][m=16nt+l16]; k'>=40 <=> mt==2 && quad>=2.
        // No max pass: |s| small (q'=XG), exp fp32-safe (validated R2+).
        const bool dead = (quad >= 2);
        bf16x4 pkP[3][3];
        #pragma unroll
        for (int nt = 0; nt < 3; ++nt) {
            float ex[3][4]; float sum = 0.f;
            #pragma unroll
            for (int mt = 0; mt < 3; ++mt)
                #pragma unroll
                for (int r = 0; r < 4; ++r) {
                    float e = (mt == 2 && dead) ? 0.f : __expf(sacc[mt][nt][r]);
                    ex[mt][r] = e; sum += e;
                }
            sum += __shfl_xor(sum, 16, 64);
            sum += __shfl_xor(sum, 32, 64);
            float inv = 1.0f / sum;
            #pragma unroll
            for (int mt = 0; mt < 3; ++mt) {
                bf16x4 pk;
                pk[0] = (bf16)(ex[mt][0] * inv); pk[1] = (bf16)(ex[mt][1] * inv);
                pk[2] = (bf16)(ex[mt][2] * inv); pk[3] = (bf16)(ex[mt][3] * inv);
                pkP[mt][nt] = pk;
            }
        }

        // ---- stage chunk A of next X (vmcnt queue is empty; wait lands after v) ----
        float4 xrA[5];
        if (more) {
            #pragma unroll
            for (int t = 0; t < 5; ++t) xrA[t] = *(const float4*)(Xn + t * 256);
        }

        // ---- v = X @ Wv : lane = v[k'=16mt+4*quad+r][e=16nt+l16] ----
        bf16x4 pkV[3][4];
        #pragma unroll
        for (int nt = 0; nt < 4; ++nt) {
            bf16x8 b0w = *(const bf16x8*)(vL + (nt * 2 + 0) * 512);
            bf16x8 b1w = *(const bf16x8*)(vL + (nt * 2 + 1) * 512);
            #pragma unroll
            for (int mt = 0; mt < 3; ++mt) {
                f32x4 acc = {0.f, 0.f, 0.f, 0.f};
                acc = mfma32(xf[mt][0], b0w, acc);
                acc = mfma32(xf[mt][1], b1w, acc);
                pkV[mt][nt] = pack4(acc);
            }
        }

        // ---- commit chunk A (current frags already in regs -> buffer reusable),
        //      issue chunk B; its wait lands after the O-residual phase ----
        float4 xrB[5];
        if (more) {
            #pragma unroll
            for (int t = 0; t < 5; ++t) *(bf16x4*)(sdst + t * 4 * XROW) = cvt4(xrA[t]);
            #pragma unroll
            for (int t = 0; t < 5; ++t) xrB[t] = *(const float4*)(Xn + (5 + t) * 256);
        }

        // ---- O^T = Wr^T@X^T (residual part) ----
        f32x4 oacc[4][3];
        #pragma unroll
        for (int mt = 0; mt < 4; ++mt) {
            bf16x8 a0 = *(const bf16x8*)(rL + (mt * 2 + 0) * 512);
            bf16x8 a1 = *(const bf16x8*)(rL + (mt * 2 + 1) * 512);
            #pragma unroll
            for (int nt = 0; nt < 3; ++nt) {
                f32x4 acc = {0.f, 0.f, 0.f, 0.f};
                acc = mfma32(a0, xf[nt][0], acc);
                acc = mfma32(a1, xf[nt][1], acc);
                oacc[mt][nt] = acc;
            }
        }

        if (more) {
            #pragma unroll
            for (int t = 0; t < 5; ++t) *(bf16x4*)(sdst + (5 + t) * 4 * XROW) = cvt4(xrB[t]);
        }

        // ---- += V^T@P^T via mfma16; k' 0..47 (40..47 = finite v * exact-zero P) ----
        #pragma unroll
        for (int mt = 0; mt < 4; ++mt)
            #pragma unroll
            for (int nt = 0; nt < 3; ++nt) {
                f32x4 acc = oacc[mt][nt];
                #pragma unroll
                for (int kt = 0; kt < 3; ++kt)
                    acc = mfma16(pkV[kt][mt], pkP[kt][nt], acc);
                oacc[mt][nt] = acc;
            }

        // ---- store: nt-outer/mt-inner -> each row's four 64 B chunks back-to-back ----
        float* Ob = Out + b * (F * 64);
        #pragma unroll
        for (int nt = 0; nt < 3; ++nt) {
            int m = nt * 16 + l16;
            if (m < F) {
                #pragma unroll
                for (int mt = 0; mt < 4; ++mt) {
                    f32x4 st;
                    st[0] = fmaxf(oacc[mt][nt][0], 0.f); st[1] = fmaxf(oacc[mt][nt][1], 0.f);
                    st[2] = fmaxf(oacc[mt][nt][2], 0.f); st[3] = fmaxf(oacc[mt][nt][3], 0.f);
                    // nontemporal: write-once output; keep X resident in L2/L3
                    __builtin_nontemporal_store(st,
                        (f32x4*)&Ob[m * 64 + mt * 16 + quad * 4]);
                }
            }
        }
    }
}

extern "C" void kernel_launch(void* const* d_in, const int* in_sizes, int n_in,
                              void* d_out, int out_size, void* d_ws, size_t ws_size,
                              hipStream_t stream) {
    const float* X  = (const float*)d_in[0];
    const float* Wq = (const float*)d_in[1];
    const float* Wk = (const float*)d_in[2];
    const float* Wv = (const float*)d_in[3];
    const float* Wr = (const float*)d_in[4];
    float* Out = (float*)d_out;
    bf16* ws = (bf16*)d_ws;   // 12288 bf16 fragment-packed G/Wv/Wr

    prep_weights<<<3, 256, 0, stream>>>(Wq, Wk, Wv, Wr, ws);
    attn_fused<<<BB / (WPB * NBW), 64 * WPB, 0, stream>>>(X, ws, Out);
}